// Round 1
// baseline (484.383 us; speedup 1.0000x reference)
//
#include <hip/hip_runtime.h>

constexpr int N   = 100000;   // nodes
constexpr int E   = 1600000;  // message edges
constexpr int EP  = 200000;   // pos scored edges
constexpr int ES  = 400000;   // total scored edges (pos+neg)
constexpr int CAP = 64;       // per-node in-edge bucket capacity (Poisson(16): P(deg>=64)~1e-18)
constexpr int XG  = 8;        // XCD groups for dst-partitioned bucket fill
constexpr int DRANGE = (N + XG - 1) / XG;   // 12500 nodes per group
constexpr int NH  = N / 2;    // agg1 half-range (profiling visibility split)
constexpr int SEGCAP = 220160; // per-group edge segment capacity (E/8=200k, +17σ margin; x256)

typedef _Float16 f16x8 __attribute__((ext_vector_type(8)));
typedef _Float16 f16x4 __attribute__((ext_vector_type(4)));
typedef _Float16 f16x2 __attribute__((ext_vector_type(2)));
typedef float    f32x4 __attribute__((ext_vector_type(4)));

// ---------------------------------------------------------------- Pass A: partition edges
// Round-13: replace 8x full-dst-rescan fill (FETCH 50MB, 77us) with a
// single-level radix partition by dst-group. Reads ei ONCE (12.8MB), packs
// (rel_dst<<17 | src) into u32 (src<2^17, rel<2^14), appends to 8 contiguous
// per-group segments. Block-aggregated offsets: LDS histogram + one global
// atomic per group per block; streaming writes.
__global__ __launch_bounds__(256) void partition_edges(const int* __restrict__ ei,
                                                       int* __restrict__ gcnt,
                                                       unsigned* __restrict__ eb) {
    __shared__ int lcnt[XG];
    __shared__ int lbase[XG];
    const int tid = threadIdx.x;
    const int e   = blockIdx.x * 256 + tid;        // E = 6250*256 exactly
    if (tid < XG) lcnt[tid] = 0;
    __syncthreads();
    const int s = __builtin_nontemporal_load(&ei[e]);       // src
    const int d = __builtin_nontemporal_load(&ei[E + e]);   // dst
    const int g   = d / DRANGE;                    // 0..7 (const-div -> magic mul)
    const int rel = d - g * DRANGE;                // < 12500 < 2^14
    const int r   = atomicAdd(&lcnt[g], 1);        // local rank within block
    __syncthreads();
    if (tid < XG) lbase[tid] = atomicAdd(&gcnt[tid], lcnt[tid]);
    __syncthreads();
    const int idx = lbase[g] + r;
    if (idx < SEGCAP) {
        const unsigned pack = ((unsigned)rel << 17) | (unsigned)s;
        __builtin_nontemporal_store(pack, &eb[(size_t)g * SEGCAP + idx]);
    }
}

// ---------------------------------------------------------------- Pass B: bucket fill
// Each XCD group (blockIdx&7 -> XCD round-robin) streams only its OWN ~800KB
// segment; per-XCD working set (3.2MB col slice + 0.8MB stream) now fits the
// 4MB L2, so partially-dirty col sectors can merge before writeback
// (round-12 WRITE_SIZE was 64MB for 6.4MB of payload).
__global__ __launch_bounds__(256) void fill_buckets2(const unsigned* __restrict__ eb,
                                                     const int* __restrict__ gcnt,
                                                     int* __restrict__ cnt,
                                                     int* __restrict__ col) {
    const int g   = blockIdx.x & (XG - 1);
    const int idx = (blockIdx.x >> 3) * 256 + threadIdx.x;
    const int cg  = min(gcnt[g], SEGCAP);
    if (idx >= cg) return;
    const unsigned pack = __builtin_nontemporal_load(&eb[(size_t)g * SEGCAP + idx]);
    const int s = (int)(pack & 0x1FFFFu);
    const int d = (int)(pack >> 17) + g * DRANGE;
    const int p = atomicAdd(&cnt[d], 1);
    if (p < CAP) col[d * CAP + p] = s;
}

// ---------------------------------------------------------------- GEMM1 (f16 MFMA)
// H[100000,128](f16) = X @ W1 (f32->f16, fp32 accum).
// Round-12: BM 128->64 (1563 blocks, ~6/CU co-resident vs 3 — round-11
// counters showed 20% occupancy, MfmaUtil 3%, VALU 5%: latency-starved) and
// register-prefetch pipeline restored (next tile's A loads + B gather staged
// in regs before current tile's MFMA). B gather packs f16x8 at load time.
__global__ __launch_bounds__(256) void gemm1_mfma(const float* __restrict__ X,
                                                  const float* __restrict__ W1,
                                                  _Float16* __restrict__ H) {
    __shared__ _Float16 As[64][40];    // [m][k], stride 40 f16 = 80 B (16B-aligned rows)
    __shared__ _Float16 Bs[128][40];   // [n][k]  (W1 tile transposed)

    const int tid  = threadIdx.x;
    const int wave = tid >> 6;
    const int lane = tid & 63;
    const int m16  = lane & 15;
    const int quad = lane >> 4;
    const int blockRow = blockIdx.x * 64;

    f32x4 acc[8] = {};      // wave covers rows [wave*16, wave*16+16) x all 128 cols

    // A staging: 64 rows x 32 k = 512 float4 -> 2/thread
    const int aR  = tid >> 2;          // wait: 512 float4 over 256 threads = 2 each
    // chunk f = tid + 256*i : r = f>>3 (0..63), kq = f&7
    // B staging: chunks c = tid + 256*i2 : n = c>>2 (0..127), kq = c&3
    float4 avA[2];
    f16x8  bvB[2];
    (void)aR;

    auto loadA = [&](int k0) {
#pragma unroll
        for (int i = 0; i < 2; ++i) {
            int f  = tid + 256 * i;
            int r  = f >> 3;
            int kq = f & 7;
            int gr = blockRow + r;
            avA[i] = (gr < N) ? *(const float4*)&X[(size_t)gr * 256 + k0 + kq * 4]
                              : make_float4(0.f, 0.f, 0.f, 0.f);
        }
    };
    auto loadB = [&](int k0) {
#pragma unroll
        for (int i2 = 0; i2 < 2; ++i2) {
            int c  = tid + 256 * i2;
            int n  = c >> 2;
            int kq = c & 3;
            f16x8 h8;
#pragma unroll
            for (int i = 0; i < 8; ++i)
                h8[i] = (_Float16)W1[(size_t)(k0 + kq * 8 + i) * 128 + n];
            bvB[i2] = h8;
        }
    };

    loadA(0); loadB(0);
    for (int k0 = 0; k0 < 256; k0 += 32) {
        __syncthreads();   // previous iteration's LDS reads complete
        // ---- store staged registers
#pragma unroll
        for (int i = 0; i < 2; ++i) {
            int f  = tid + 256 * i;
            int r  = f >> 3;
            int kq = f & 7;
            f16x4 h4;
            h4[0] = (_Float16)avA[i].x; h4[1] = (_Float16)avA[i].y;
            h4[2] = (_Float16)avA[i].z; h4[3] = (_Float16)avA[i].w;
            *(f16x4*)&As[r][kq * 4] = h4;
            int c  = f;                 // same chunk index for B
            int n  = c >> 2;
            int bq = c & 3;
            *(f16x8*)&Bs[n][bq * 8] = bvB[i];
        }
        __syncthreads();
        // ---- issue next tile's global loads (hide under MFMA below)
        if (k0 + 32 < 256) { loadA(k0 + 32); loadB(k0 + 32); }
        // ---- compute on current LDS tile
        f16x8 afrag = *(const f16x8*)&As[wave * 16 + m16][quad * 8];
#pragma unroll
        for (int nt = 0; nt < 8; ++nt) {
            f16x8 bfrag = *(const f16x8*)&Bs[nt * 16 + m16][quad * 8];
            acc[nt] = __builtin_amdgcn_mfma_f32_16x16x32_f16(afrag, bfrag, acc[nt], 0, 0, 0);
        }
    }
    // ---- epilogue: C/D layout col=lane&15, row=quad*4+r
#pragma unroll
    for (int nt = 0; nt < 8; ++nt)
#pragma unroll
        for (int r = 0; r < 4; ++r) {
            int gm = blockRow + wave * 16 + quad * 4 + r;
            int gn = nt * 16 + m16;
            if (gm < N) H[(size_t)gm * 128 + gn] = (_Float16)acc[nt][r];
        }
}

// ---------------------------------------------------------------- Fused agg1 + gemm2
// One wave per node; lane l owns feats [2l, 2l+1]; depth-4 double-buffered
// prefetch (proven best). Two half-range launches for profiler visibility.
__global__ __launch_bounds__(256) void agg1_gemm2(const _Float16* __restrict__ H,
                                                  const int* __restrict__ cnt,
                                                  const int* __restrict__ col,
                                                  const float* __restrict__ b1,
                                                  const float* __restrict__ W2,
                                                  float* __restrict__ Z,
                                                  int nbase, int ncount) {
    const int nr   = (blockIdx.x * blockDim.x + threadIdx.x) >> 6;
    const int lane = threadIdx.x & 63;
    if (nr >= ncount) return;
    const int n = nbase + nr;
    const int c = min(cnt[n], CAP);

    int sv = n;
    if (lane < c) sv = col[n * CAP + lane];
    const float dvw = rsqrtf((float)cnt[sv] + 1.0f);
    const float dv  = (lane <= c) ? dvw : 0.0f;

    const _Float16* hbase = H + lane * 2;
    const int ned4 = (c + 1 + 3) & ~3;

    f16x2 va[4]; float wa[4];
#pragma unroll
    for (int t = 0; t < 4; ++t) {
        const int   e = min(t, 63);
        const int   s = __shfl(sv, e);
        wa[t]         = __shfl(dv, e);
        va[t] = *(const f16x2*)&hbase[(size_t)s * 128];
    }
    float ax = 0.f, ay = 0.f;
    for (int j = 4; j < ned4; j += 4) {
        f16x2 vb[4]; float wb[4];
#pragma unroll
        for (int t = 0; t < 4; ++t) {
            const int   e = min(j + t, 63);
            const int   s = __shfl(sv, e);
            wb[t]         = __shfl(dv, e);
            vb[t] = *(const f16x2*)&hbase[(size_t)s * 128];
        }
#pragma unroll
        for (int t = 0; t < 4; ++t) {
            ax = fmaf(wa[t], (float)va[t][0], ax);
            ay = fmaf(wa[t], (float)va[t][1], ay);
            va[t] = vb[t]; wa[t] = wb[t];
        }
    }
#pragma unroll
    for (int t = 0; t < 4; ++t) {
        ax = fmaf(wa[t], (float)va[t][0], ax);
        ay = fmaf(wa[t], (float)va[t][1], ay);
    }

    const float dn = __shfl(dv, c);         // dinv[n]
    const float2 b = *(const float2*)&b1[lane * 2];
    const float hr0 = fmaxf(ax * dn + b.x, 0.f);
    const float hr1 = fmaxf(ay * dn + b.y, 0.f);

    const float4 wa0 = *(const float4*)&W2[(size_t)(lane * 2) * 8];
    const float4 wa1 = *(const float4*)&W2[(size_t)(lane * 2) * 8 + 4];
    const float4 wb0 = *(const float4*)&W2[(size_t)(lane * 2 + 1) * 8];
    const float4 wb1 = *(const float4*)&W2[(size_t)(lane * 2 + 1) * 8 + 4];
    float p[8];
    p[0] = hr0 * wa0.x + hr1 * wb0.x;
    p[1] = hr0 * wa0.y + hr1 * wb0.y;
    p[2] = hr0 * wa0.z + hr1 * wb0.z;
    p[3] = hr0 * wa0.w + hr1 * wb0.w;
    p[4] = hr0 * wa1.x + hr1 * wb1.x;
    p[5] = hr0 * wa1.y + hr1 * wb1.y;
    p[6] = hr0 * wa1.z + hr1 * wb1.z;
    p[7] = hr0 * wa1.w + hr1 * wb1.w;
#pragma unroll
    for (int off = 32; off > 0; off >>= 1)
#pragma unroll
        for (int j = 0; j < 8; ++j) p[j] += __shfl_xor(p[j], off);
    if (lane == 0) {
        *(float4*)&Z[(size_t)n * 8]     = make_float4(p[0], p[1], p[2], p[3]);
        *(float4*)&Z[(size_t)n * 8 + 4] = make_float4(p[4], p[5], p[6], p[7]);
    }
}

// ---------------------------------------------------------------- Aggregation layer 2 (F=8)
// Thread per node, depth-4 prefetch; 64-thread blocks for CU load-balance.
__global__ __launch_bounds__(64) void agg2(const float* __restrict__ Z,
                                           const int* __restrict__ cnt,
                                           const int* __restrict__ col,
                                           const float* __restrict__ b2,
                                           float* __restrict__ ZA) {
    const int n = blockIdx.x * blockDim.x + threadIdx.x;
    if (n >= N) return;
    const int c = min(cnt[n], CAP);
    float acc[8] = {};

    float4 va0[4], va1[4]; float wv[4];
#pragma unroll
    for (int t = 0; t < 4; ++t) {
        const int s = (t < c) ? col[n * CAP + t] : n;
        wv[t]  = (t < c) ? rsqrtf((float)cnt[s] + 1.0f) : 0.0f;
        va0[t] = *(const float4*)&Z[(size_t)s * 8];
        va1[t] = *(const float4*)&Z[(size_t)s * 8 + 4];
    }
    for (int j = 4; j + 4 <= c + 4; j += 4) {
        float4 vb0[4], vb1[4]; float wb[4];
#pragma unroll
        for (int t = 0; t < 4; ++t) {
            const int jt = j + t;
            const int s  = (jt < c) ? col[n * CAP + jt] : n;
            wb[t]  = (jt < c) ? rsqrtf((float)cnt[s] + 1.0f) : 0.0f;
            vb0[t] = *(const float4*)&Z[(size_t)s * 8];
            vb1[t] = *(const float4*)&Z[(size_t)s * 8 + 4];
        }
#pragma unroll
        for (int t = 0; t < 4; ++t) {
            const float w = wv[t];
            acc[0] = fmaf(w, va0[t].x, acc[0]); acc[1] = fmaf(w, va0[t].y, acc[1]);
            acc[2] = fmaf(w, va0[t].z, acc[2]); acc[3] = fmaf(w, va0[t].w, acc[3]);
            acc[4] = fmaf(w, va1[t].x, acc[4]); acc[5] = fmaf(w, va1[t].y, acc[5]);
            acc[6] = fmaf(w, va1[t].z, acc[6]); acc[7] = fmaf(w, va1[t].w, acc[7]);
            va0[t] = vb0[t]; va1[t] = vb1[t]; wv[t] = wb[t];
        }
    }
#pragma unroll
    for (int t = 0; t < 4; ++t) {
        const float w = wv[t];
        acc[0] = fmaf(w, va0[t].x, acc[0]); acc[1] = fmaf(w, va0[t].y, acc[1]);
        acc[2] = fmaf(w, va0[t].z, acc[2]); acc[3] = fmaf(w, va0[t].w, acc[3]);
        acc[4] = fmaf(w, va1[t].x, acc[4]); acc[5] = fmaf(w, va1[t].y, acc[5]);
        acc[6] = fmaf(w, va1[t].z, acc[6]); acc[7] = fmaf(w, va1[t].w, acc[7]);
    }

    const float dn = rsqrtf((float)c + 1.0f);
    const float4 zn0 = *(const float4*)&Z[(size_t)n * 8];
    const float4 zn1 = *(const float4*)&Z[(size_t)n * 8 + 4];
    float o[8];
    o[0] = (acc[0] + dn * zn0.x) * dn + b2[0];
    o[1] = (acc[1] + dn * zn0.y) * dn + b2[1];
    o[2] = (acc[2] + dn * zn0.z) * dn + b2[2];
    o[3] = (acc[3] + dn * zn0.w) * dn + b2[3];
    o[4] = (acc[4] + dn * zn1.x) * dn + b2[4];
    o[5] = (acc[5] + dn * zn1.y) * dn + b2[5];
    o[6] = (acc[6] + dn * zn1.z) * dn + b2[6];
    o[7] = (acc[7] + dn * zn1.w) * dn + b2[7];
    *(float4*)&ZA[(size_t)n * 8]     = make_float4(o[0], o[1], o[2], o[3]);
    *(float4*)&ZA[(size_t)n * 8 + 4] = make_float4(o[4], o[5], o[6], o[7]);
}

// ---------------------------------------------------------------- Edge scoring
__global__ __launch_bounds__(256) void score(const float* __restrict__ ZA,
                                             const int* __restrict__ pe,
                                             const int* __restrict__ ne,
                                             float* __restrict__ out) {
    const int e = blockIdx.x * blockDim.x + threadIdx.x;
    if (e >= ES) return;
    int a, b;
    if (e < EP) { a = pe[e];      b = pe[EP + e]; }
    else        { a = ne[e - EP]; b = ne[e];      }
    const float4 xa0 = *(const float4*)&ZA[(size_t)a * 8];
    const float4 xa1 = *(const float4*)&ZA[(size_t)a * 8 + 4];
    const float4 xb0 = *(const float4*)&ZA[(size_t)b * 8];
    const float4 xb1 = *(const float4*)&ZA[(size_t)b * 8 + 4];
    out[e] = xa0.x * xb0.x + xa0.y * xb0.y + xa0.z * xb0.z + xa0.w * xb0.w +
             xa1.x * xb1.x + xa1.y * xb1.y + xa1.z * xb1.z + xa1.w * xb1.w;
}

// ---------------------------------------------------------------- launch

extern "C" void kernel_launch(void* const* d_in, const int* in_sizes, int n_in,
                              void* d_out, int out_size, void* d_ws, size_t ws_size,
                              hipStream_t stream) {
    const float* x  = (const float*)d_in[0];
    const int*   ei = (const int*)d_in[1];   // [2, 1.6M] row-major
    const int*   pe = (const int*)d_in[2];   // [2, 200k]
    const int*   ne = (const int*)d_in[3];   // [2, 200k]
    const float* W1 = (const float*)d_in[4];
    const float* b1 = (const float*)d_in[5];
    const float* W2 = (const float*)d_in[6];
    const float* b2 = (const float*)d_in[7];
    float* out = (float*)d_out;

    char* ws = (char*)d_ws;
    size_t off = 0;
    auto carve = [&](size_t bytes) {
        char* p = ws + off;
        off += (bytes + 255) & ~(size_t)255;
        return p;
    };
    int*       cnt  = (int*)      carve((size_t)N * sizeof(int));            // 0.4 MB
    int*       gcnt = (int*)      carve((size_t)XG * sizeof(int));           // 32 B (adjacent to cnt)
    unsigned*  eb   = (unsigned*) carve((size_t)XG * SEGCAP * sizeof(unsigned)); // 7.0 MB
    int*       col  = (int*)      carve((size_t)N * CAP * sizeof(int));      // 25.6 MB
    _Float16*  H    = (_Float16*) carve((size_t)N * 128 * sizeof(_Float16)); // 25.6 MB
    float*     Z    = (float*)    carve((size_t)N * 8 * sizeof(float));      // 3.2 MB
    float*     ZA   = (float*)    carve((size_t)N * 8 * sizeof(float));      // 3.2 MB

    // one memset covers cnt + gcnt (gcnt carved immediately after cnt)
    hipMemsetAsync(cnt, 0, (size_t)((char*)gcnt - (char*)cnt) + XG * sizeof(int), stream);
    partition_edges<<<E / 256, 256, 0, stream>>>(ei, gcnt, eb);
    fill_buckets2  <<<XG * (SEGCAP / 256), 256, 0, stream>>>(eb, gcnt, cnt, col);
    gemm1_mfma     <<<(N + 63) / 64, 256, 0, stream>>>(x, W1, H);
    agg1_gemm2     <<<(NH * 64 + 255) / 256, 256, 0, stream>>>(H, cnt, col, b1, W2, Z, 0, NH);
    agg1_gemm2     <<<((N - NH) * 64 + 255) / 256, 256, 0, stream>>>(H, cnt, col, b1, W2, Z, NH, N - NH);
    agg2           <<<(N + 63) / 64, 64, 0, stream>>>(Z, cnt, col, b2, ZA);
    score          <<<(ES + 255) / 256, 256, 0, stream>>>(ZA, pe, ne, out);
}

// Round 2
// 423.648 us; speedup vs baseline: 1.1434x; 1.1434x over previous
//
#include <hip/hip_runtime.h>

constexpr int N   = 100000;   // nodes
constexpr int E   = 1600000;  // message edges
constexpr int EP  = 200000;   // pos scored edges
constexpr int ES  = 400000;   // total scored edges (pos+neg)
constexpr int CAP = 64;       // per-node in-edge bucket capacity (Poisson(16): P(deg>=64)~1e-18)
constexpr int XG  = 8;        // XCD groups for dst-partitioned bucket fill
constexpr int DRANGE = (N + XG - 1) / XG;   // 12500 nodes per group
constexpr int NH  = N / 2;    // agg1 half-range (profiling visibility split)
constexpr int SEGCAP = 220160; // per-group edge segment capacity (E/8=200k, +17sigma margin; x256)
constexpr int EPB = 8192;     // edges per partition block
constexpr int PBS = 1024;     // partition block size
constexpr int NPB = (E + EPB - 1) / EPB;    // 196 partition blocks

typedef _Float16 f16x8 __attribute__((ext_vector_type(8)));
typedef _Float16 f16x4 __attribute__((ext_vector_type(4)));
typedef _Float16 f16x2 __attribute__((ext_vector_type(2)));
typedef float    f32x4 __attribute__((ext_vector_type(4)));

// ---------------------------------------------------------------- Pass A: partition edges
// Round-14: round-13's version spent 75us (2.8% HBM, 1% VALU) serialized on
// 50K global atomics to ONE cache line (6250 blocks x 8 groups). Now 196
// blocks x 8192 edges, two phases: (1) LDS histogram (per-edge LDS atomics
// measured negligible: 302K conflict-cycles device-wide), (2) ONE global
// atomic per group per block (1568 total, 32x fewer), then re-read the
// block's 64KB chunk (L2-warm) and scatter at LDS-ranked positions.
__global__ __launch_bounds__(1024) void partition_edges(const int* __restrict__ ei,
                                                        int* __restrict__ gcnt,
                                                        unsigned* __restrict__ eb) {
    __shared__ int lh[XG];   // block histogram
    __shared__ int rk[XG];   // running rank counters (init = global base)
    const int tid = threadIdx.x;
    const int e0  = blockIdx.x * EPB;
    if (tid < XG) lh[tid] = 0;
    __syncthreads();
    // phase 1: histogram of dst-groups (normal loads -> chunk stays L2-resident)
#pragma unroll
    for (int i = 0; i < EPB; i += PBS) {
        const int e = e0 + i + tid;
        if (e < E) {
            const int d = ei[E + e];
            atomicAdd(&lh[d / DRANGE], 1);
        }
    }
    __syncthreads();
    if (tid < XG) rk[tid] = atomicAdd(&gcnt[tid], lh[tid]);  // one hot atomic per group per block
    __syncthreads();
    // phase 2: rank + scatter (re-reads hit L2)
#pragma unroll
    for (int i = 0; i < EPB; i += PBS) {
        const int e = e0 + i + tid;
        if (e < E) {
            const int s   = ei[e];
            const int d   = ei[E + e];
            const int g   = d / DRANGE;
            const int rel = d - g * DRANGE;            // < 12500 < 2^14
            const int p   = atomicAdd(&rk[g], 1);
            if (p < SEGCAP)
                eb[(size_t)g * SEGCAP + p] = ((unsigned)rel << 17) | (unsigned)s;
        }
    }
}

// ---------------------------------------------------------------- Pass B: bucket fill
// Each XCD group (blockIdx&7 -> XCD round-robin) streams only its OWN ~800KB
// segment; per-XCD working set (3.2MB col slice + 0.8MB stream) ~ 4MB L2.
__global__ __launch_bounds__(256) void fill_buckets2(const unsigned* __restrict__ eb,
                                                     const int* __restrict__ gcnt,
                                                     int* __restrict__ cnt,
                                                     int* __restrict__ col) {
    const int g   = blockIdx.x & (XG - 1);
    const int idx = (blockIdx.x >> 3) * 256 + threadIdx.x;
    const int cg  = min(gcnt[g], SEGCAP);
    if (idx >= cg) return;
    const unsigned pack = __builtin_nontemporal_load(&eb[(size_t)g * SEGCAP + idx]);
    const int s = (int)(pack & 0x1FFFFu);
    const int d = (int)(pack >> 17) + g * DRANGE;
    const int p = atomicAdd(&cnt[d], 1);
    if (p < CAP) col[d * CAP + p] = s;
}

// ---------------------------------------------------------------- GEMM1 (f16 MFMA)
// H[100000,128](f16) = X @ W1 (f32->f16, fp32 accum).
// Round-12: BM 128->64 (1563 blocks, ~6/CU co-resident vs 3 — round-11
// counters showed 20% occupancy, MfmaUtil 3%, VALU 5%: latency-starved) and
// register-prefetch pipeline restored (next tile's A loads + B gather staged
// in regs before current tile's MFMA). B gather packs f16x8 at load time.
__global__ __launch_bounds__(256) void gemm1_mfma(const float* __restrict__ X,
                                                  const float* __restrict__ W1,
                                                  _Float16* __restrict__ H) {
    __shared__ _Float16 As[64][40];    // [m][k], stride 40 f16 = 80 B (16B-aligned rows)
    __shared__ _Float16 Bs[128][40];   // [n][k]  (W1 tile transposed)

    const int tid  = threadIdx.x;
    const int wave = tid >> 6;
    const int lane = tid & 63;
    const int m16  = lane & 15;
    const int quad = lane >> 4;
    const int blockRow = blockIdx.x * 64;

    f32x4 acc[8] = {};      // wave covers rows [wave*16, wave*16+16) x all 128 cols

    // A staging: 64 rows x 32 k = 512 float4 -> 2/thread
    const int aR  = tid >> 2;          // wait: 512 float4 over 256 threads = 2 each
    // chunk f = tid + 256*i : r = f>>3 (0..63), kq = f&7
    // B staging: chunks c = tid + 256*i2 : n = c>>2 (0..127), kq = c&3
    float4 avA[2];
    f16x8  bvB[2];
    (void)aR;

    auto loadA = [&](int k0) {
#pragma unroll
        for (int i = 0; i < 2; ++i) {
            int f  = tid + 256 * i;
            int r  = f >> 3;
            int kq = f & 7;
            int gr = blockRow + r;
            avA[i] = (gr < N) ? *(const float4*)&X[(size_t)gr * 256 + k0 + kq * 4]
                              : make_float4(0.f, 0.f, 0.f, 0.f);
        }
    };
    auto loadB = [&](int k0) {
#pragma unroll
        for (int i2 = 0; i2 < 2; ++i2) {
            int c  = tid + 256 * i2;
            int n  = c >> 2;
            int kq = c & 3;
            f16x8 h8;
#pragma unroll
            for (int i = 0; i < 8; ++i)
                h8[i] = (_Float16)W1[(size_t)(k0 + kq * 8 + i) * 128 + n];
            bvB[i2] = h8;
        }
    };

    loadA(0); loadB(0);
    for (int k0 = 0; k0 < 256; k0 += 32) {
        __syncthreads();   // previous iteration's LDS reads complete
        // ---- store staged registers
#pragma unroll
        for (int i = 0; i < 2; ++i) {
            int f  = tid + 256 * i;
            int r  = f >> 3;
            int kq = f & 7;
            f16x4 h4;
            h4[0] = (_Float16)avA[i].x; h4[1] = (_Float16)avA[i].y;
            h4[2] = (_Float16)avA[i].z; h4[3] = (_Float16)avA[i].w;
            *(f16x4*)&As[r][kq * 4] = h4;
            int c  = f;                 // same chunk index for B
            int n  = c >> 2;
            int bq = c & 3;
            *(f16x8*)&Bs[n][bq * 8] = bvB[i];
        }
        __syncthreads();
        // ---- issue next tile's global loads (hide under MFMA below)
        if (k0 + 32 < 256) { loadA(k0 + 32); loadB(k0 + 32); }
        // ---- compute on current LDS tile
        f16x8 afrag = *(const f16x8*)&As[wave * 16 + m16][quad * 8];
#pragma unroll
        for (int nt = 0; nt < 8; ++nt) {
            f16x8 bfrag = *(const f16x8*)&Bs[nt * 16 + m16][quad * 8];
            acc[nt] = __builtin_amdgcn_mfma_f32_16x16x32_f16(afrag, bfrag, acc[nt], 0, 0, 0);
        }
    }
    // ---- epilogue: C/D layout col=lane&15, row=quad*4+r
#pragma unroll
    for (int nt = 0; nt < 8; ++nt)
#pragma unroll
        for (int r = 0; r < 4; ++r) {
            int gm = blockRow + wave * 16 + quad * 4 + r;
            int gn = nt * 16 + m16;
            if (gm < N) H[(size_t)gm * 128 + gn] = (_Float16)acc[nt][r];
        }
}

// ---------------------------------------------------------------- Fused agg1 + gemm2
// One wave per node; lane l owns feats [2l, 2l+1]; depth-4 double-buffered
// prefetch (proven best). Two half-range launches for profiler visibility.
__global__ __launch_bounds__(256) void agg1_gemm2(const _Float16* __restrict__ H,
                                                  const int* __restrict__ cnt,
                                                  const int* __restrict__ col,
                                                  const float* __restrict__ b1,
                                                  const float* __restrict__ W2,
                                                  float* __restrict__ Z,
                                                  int nbase, int ncount) {
    const int nr   = (blockIdx.x * blockDim.x + threadIdx.x) >> 6;
    const int lane = threadIdx.x & 63;
    if (nr >= ncount) return;
    const int n = nbase + nr;
    const int c = min(cnt[n], CAP);

    int sv = n;
    if (lane < c) sv = col[n * CAP + lane];
    const float dvw = rsqrtf((float)cnt[sv] + 1.0f);
    const float dv  = (lane <= c) ? dvw : 0.0f;

    const _Float16* hbase = H + lane * 2;
    const int ned4 = (c + 1 + 3) & ~3;

    f16x2 va[4]; float wa[4];
#pragma unroll
    for (int t = 0; t < 4; ++t) {
        const int   e = min(t, 63);
        const int   s = __shfl(sv, e);
        wa[t]         = __shfl(dv, e);
        va[t] = *(const f16x2*)&hbase[(size_t)s * 128];
    }
    float ax = 0.f, ay = 0.f;
    for (int j = 4; j < ned4; j += 4) {
        f16x2 vb[4]; float wb[4];
#pragma unroll
        for (int t = 0; t < 4; ++t) {
            const int   e = min(j + t, 63);
            const int   s = __shfl(sv, e);
            wb[t]         = __shfl(dv, e);
            vb[t] = *(const f16x2*)&hbase[(size_t)s * 128];
        }
#pragma unroll
        for (int t = 0; t < 4; ++t) {
            ax = fmaf(wa[t], (float)va[t][0], ax);
            ay = fmaf(wa[t], (float)va[t][1], ay);
            va[t] = vb[t]; wa[t] = wb[t];
        }
    }
#pragma unroll
    for (int t = 0; t < 4; ++t) {
        ax = fmaf(wa[t], (float)va[t][0], ax);
        ay = fmaf(wa[t], (float)va[t][1], ay);
    }

    const float dn = __shfl(dv, c);         // dinv[n]
    const float2 b = *(const float2*)&b1[lane * 2];
    const float hr0 = fmaxf(ax * dn + b.x, 0.f);
    const float hr1 = fmaxf(ay * dn + b.y, 0.f);

    const float4 wa0 = *(const float4*)&W2[(size_t)(lane * 2) * 8];
    const float4 wa1 = *(const float4*)&W2[(size_t)(lane * 2) * 8 + 4];
    const float4 wb0 = *(const float4*)&W2[(size_t)(lane * 2 + 1) * 8];
    const float4 wb1 = *(const float4*)&W2[(size_t)(lane * 2 + 1) * 8 + 4];
    float p[8];
    p[0] = hr0 * wa0.x + hr1 * wb0.x;
    p[1] = hr0 * wa0.y + hr1 * wb0.y;
    p[2] = hr0 * wa0.z + hr1 * wb0.z;
    p[3] = hr0 * wa0.w + hr1 * wb0.w;
    p[4] = hr0 * wa1.x + hr1 * wb1.x;
    p[5] = hr0 * wa1.y + hr1 * wb1.y;
    p[6] = hr0 * wa1.z + hr1 * wb1.z;
    p[7] = hr0 * wa1.w + hr1 * wb1.w;
#pragma unroll
    for (int off = 32; off > 0; off >>= 1)
#pragma unroll
        for (int j = 0; j < 8; ++j) p[j] += __shfl_xor(p[j], off);
    if (lane == 0) {
        *(float4*)&Z[(size_t)n * 8]     = make_float4(p[0], p[1], p[2], p[3]);
        *(float4*)&Z[(size_t)n * 8 + 4] = make_float4(p[4], p[5], p[6], p[7]);
    }
}

// ---------------------------------------------------------------- Aggregation layer 2 (F=8)
// Thread per node, depth-4 prefetch; 64-thread blocks for CU load-balance.
__global__ __launch_bounds__(64) void agg2(const float* __restrict__ Z,
                                           const int* __restrict__ cnt,
                                           const int* __restrict__ col,
                                           const float* __restrict__ b2,
                                           float* __restrict__ ZA) {
    const int n = blockIdx.x * blockDim.x + threadIdx.x;
    if (n >= N) return;
    const int c = min(cnt[n], CAP);
    float acc[8] = {};

    float4 va0[4], va1[4]; float wv[4];
#pragma unroll
    for (int t = 0; t < 4; ++t) {
        const int s = (t < c) ? col[n * CAP + t] : n;
        wv[t]  = (t < c) ? rsqrtf((float)cnt[s] + 1.0f) : 0.0f;
        va0[t] = *(const float4*)&Z[(size_t)s * 8];
        va1[t] = *(const float4*)&Z[(size_t)s * 8 + 4];
    }
    for (int j = 4; j + 4 <= c + 4; j += 4) {
        float4 vb0[4], vb1[4]; float wb[4];
#pragma unroll
        for (int t = 0; t < 4; ++t) {
            const int jt = j + t;
            const int s  = (jt < c) ? col[n * CAP + jt] : n;
            wb[t]  = (jt < c) ? rsqrtf((float)cnt[s] + 1.0f) : 0.0f;
            vb0[t] = *(const float4*)&Z[(size_t)s * 8];
            vb1[t] = *(const float4*)&Z[(size_t)s * 8 + 4];
        }
#pragma unroll
        for (int t = 0; t < 4; ++t) {
            const float w = wv[t];
            acc[0] = fmaf(w, va0[t].x, acc[0]); acc[1] = fmaf(w, va0[t].y, acc[1]);
            acc[2] = fmaf(w, va0[t].z, acc[2]); acc[3] = fmaf(w, va0[t].w, acc[3]);
            acc[4] = fmaf(w, va1[t].x, acc[4]); acc[5] = fmaf(w, va1[t].y, acc[5]);
            acc[6] = fmaf(w, va1[t].z, acc[6]); acc[7] = fmaf(w, va1[t].w, acc[7]);
            va0[t] = vb0[t]; va1[t] = vb1[t]; wv[t] = wb[t];
        }
    }
#pragma unroll
    for (int t = 0; t < 4; ++t) {
        const float w = wv[t];
        acc[0] = fmaf(w, va0[t].x, acc[0]); acc[1] = fmaf(w, va0[t].y, acc[1]);
        acc[2] = fmaf(w, va0[t].z, acc[2]); acc[3] = fmaf(w, va0[t].w, acc[3]);
        acc[4] = fmaf(w, va1[t].x, acc[4]); acc[5] = fmaf(w, va1[t].y, acc[5]);
        acc[6] = fmaf(w, va1[t].z, acc[6]); acc[7] = fmaf(w, va1[t].w, acc[7]);
    }

    const float dn = rsqrtf((float)c + 1.0f);
    const float4 zn0 = *(const float4*)&Z[(size_t)n * 8];
    const float4 zn1 = *(const float4*)&Z[(size_t)n * 8 + 4];
    float o[8];
    o[0] = (acc[0] + dn * zn0.x) * dn + b2[0];
    o[1] = (acc[1] + dn * zn0.y) * dn + b2[1];
    o[2] = (acc[2] + dn * zn0.z) * dn + b2[2];
    o[3] = (acc[3] + dn * zn0.w) * dn + b2[3];
    o[4] = (acc[4] + dn * zn1.x) * dn + b2[4];
    o[5] = (acc[5] + dn * zn1.y) * dn + b2[5];
    o[6] = (acc[6] + dn * zn1.z) * dn + b2[6];
    o[7] = (acc[7] + dn * zn1.w) * dn + b2[7];
    *(float4*)&ZA[(size_t)n * 8]     = make_float4(o[0], o[1], o[2], o[3]);
    *(float4*)&ZA[(size_t)n * 8 + 4] = make_float4(o[4], o[5], o[6], o[7]);
}

// ---------------------------------------------------------------- Edge scoring
__global__ __launch_bounds__(256) void score(const float* __restrict__ ZA,
                                             const int* __restrict__ pe,
                                             const int* __restrict__ ne,
                                             float* __restrict__ out) {
    const int e = blockIdx.x * blockDim.x + threadIdx.x;
    if (e >= ES) return;
    int a, b;
    if (e < EP) { a = pe[e];      b = pe[EP + e]; }
    else        { a = ne[e - EP]; b = ne[e];      }
    const float4 xa0 = *(const float4*)&ZA[(size_t)a * 8];
    const float4 xa1 = *(const float4*)&ZA[(size_t)a * 8 + 4];
    const float4 xb0 = *(const float4*)&ZA[(size_t)b * 8];
    const float4 xb1 = *(const float4*)&ZA[(size_t)b * 8 + 4];
    out[e] = xa0.x * xb0.x + xa0.y * xb0.y + xa0.z * xb0.z + xa0.w * xb0.w +
             xa1.x * xb1.x + xa1.y * xb1.y + xa1.z * xb1.z + xa1.w * xb1.w;
}

// ---------------------------------------------------------------- launch

extern "C" void kernel_launch(void* const* d_in, const int* in_sizes, int n_in,
                              void* d_out, int out_size, void* d_ws, size_t ws_size,
                              hipStream_t stream) {
    const float* x  = (const float*)d_in[0];
    const int*   ei = (const int*)d_in[1];   // [2, 1.6M] row-major
    const int*   pe = (const int*)d_in[2];   // [2, 200k]
    const int*   ne = (const int*)d_in[3];   // [2, 200k]
    const float* W1 = (const float*)d_in[4];
    const float* b1 = (const float*)d_in[5];
    const float* W2 = (const float*)d_in[6];
    const float* b2 = (const float*)d_in[7];
    float* out = (float*)d_out;

    char* ws = (char*)d_ws;
    size_t off = 0;
    auto carve = [&](size_t bytes) {
        char* p = ws + off;
        off += (bytes + 255) & ~(size_t)255;
        return p;
    };
    int*       cnt  = (int*)      carve((size_t)N * sizeof(int));            // 0.4 MB
    int*       gcnt = (int*)      carve((size_t)XG * sizeof(int));           // 32 B (adjacent to cnt)
    unsigned*  eb   = (unsigned*) carve((size_t)XG * SEGCAP * sizeof(unsigned)); // 7.0 MB
    int*       col  = (int*)      carve((size_t)N * CAP * sizeof(int));      // 25.6 MB
    _Float16*  H    = (_Float16*) carve((size_t)N * 128 * sizeof(_Float16)); // 25.6 MB
    float*     Z    = (float*)    carve((size_t)N * 8 * sizeof(float));      // 3.2 MB
    float*     ZA   = (float*)    carve((size_t)N * 8 * sizeof(float));      // 3.2 MB

    // one memset covers cnt + gcnt (gcnt carved immediately after cnt)
    hipMemsetAsync(cnt, 0, (size_t)((char*)gcnt - (char*)cnt) + XG * sizeof(int), stream);
    partition_edges<<<NPB, PBS, 0, stream>>>(ei, gcnt, eb);
    fill_buckets2  <<<XG * (SEGCAP / 256), 256, 0, stream>>>(eb, gcnt, cnt, col);
    gemm1_mfma     <<<(N + 63) / 64, 256, 0, stream>>>(x, W1, H);
    agg1_gemm2     <<<(NH * 64 + 255) / 256, 256, 0, stream>>>(H, cnt, col, b1, W2, Z, 0, NH);
    agg1_gemm2     <<<((N - NH) * 64 + 255) / 256, 256, 0, stream>>>(H, cnt, col, b1, W2, Z, NH, N - NH);
    agg2           <<<(N + 63) / 64, 64, 0, stream>>>(Z, cnt, col, b2, ZA);
    score          <<<(ES + 255) / 256, 256, 0, stream>>>(ZA, pe, ne, out);
}

// Round 4
// 417.667 us; speedup vs baseline: 1.1597x; 1.0143x over previous
//
#include <hip/hip_runtime.h>

constexpr int N   = 100000;   // nodes
constexpr int E   = 1600000;  // message edges
constexpr int EP  = 200000;   // pos scored edges
constexpr int ES  = 400000;   // total scored edges (pos+neg)
constexpr int CAP = 64;       // per-node in-edge bucket capacity (Poisson(16): P(deg>=64)~1e-18)
constexpr int XG  = 8;        // XCD groups for dst-partitioned bucket fill
constexpr int DRANGE = (N + XG - 1) / XG;   // 12500 nodes per group
constexpr int NH  = N / 2;    // agg1 half-range (profiling visibility split)
constexpr int SEGCAP = 220160; // per-group edge segment capacity (E/8=200k, +17sigma margin; x256)
constexpr int EPB = 8192;     // edges per partition block
constexpr int PBS = 1024;     // partition block size
constexpr int NPB = (E + EPB - 1) / EPB;    // 196 partition blocks
constexpr int BSTR = 264;     // gemm1 LDS B k-stride (f16): 264*2B=528B -> bank (4n+4q)%32, 2-way max

typedef _Float16 f16x8 __attribute__((ext_vector_type(8)));
typedef _Float16 f16x4 __attribute__((ext_vector_type(4)));
typedef _Float16 f16x2 __attribute__((ext_vector_type(2)));
typedef float    f32x4 __attribute__((ext_vector_type(4)));

// ---------------------------------------------------------------- Pass A: partition edges
// Round-14: 196 blocks x 8192 edges, two phases: (1) LDS histogram, (2) ONE
// global atomic per group per block (1568 total), then re-read the block's
// 64KB chunk (L2-warm) and scatter at LDS-ranked positions.
__global__ __launch_bounds__(1024) void partition_edges(const int* __restrict__ ei,
                                                        int* __restrict__ gcnt,
                                                        unsigned* __restrict__ eb) {
    __shared__ int lh[XG];   // block histogram
    __shared__ int rk[XG];   // running rank counters (init = global base)
    const int tid = threadIdx.x;
    const int e0  = blockIdx.x * EPB;
    if (tid < XG) lh[tid] = 0;
    __syncthreads();
#pragma unroll
    for (int i = 0; i < EPB; i += PBS) {
        const int e = e0 + i + tid;
        if (e < E) {
            const int d = ei[E + e];
            atomicAdd(&lh[d / DRANGE], 1);
        }
    }
    __syncthreads();
    if (tid < XG) rk[tid] = atomicAdd(&gcnt[tid], lh[tid]);  // one hot atomic per group per block
    __syncthreads();
#pragma unroll
    for (int i = 0; i < EPB; i += PBS) {
        const int e = e0 + i + tid;
        if (e < E) {
            const int s   = ei[e];
            const int d   = ei[E + e];
            const int g   = d / DRANGE;
            const int rel = d - g * DRANGE;            // < 12500 < 2^14
            const int p   = atomicAdd(&rk[g], 1);
            if (p < SEGCAP)
                eb[(size_t)g * SEGCAP + p] = ((unsigned)rel << 17) | (unsigned)s;
        }
    }
}

// ---------------------------------------------------------------- Pass B: bucket fill
__global__ __launch_bounds__(256) void fill_buckets2(const unsigned* __restrict__ eb,
                                                     const int* __restrict__ gcnt,
                                                     int* __restrict__ cnt,
                                                     int* __restrict__ col) {
    const int g   = blockIdx.x & (XG - 1);
    const int idx = (blockIdx.x >> 3) * 256 + threadIdx.x;
    const int cg  = min(gcnt[g], SEGCAP);
    if (idx >= cg) return;
    const unsigned pack = __builtin_nontemporal_load(&eb[(size_t)g * SEGCAP + idx]);
    const int s = (int)(pack & 0x1FFFFu);
    const int d = (int)(pack >> 17) + g * DRANGE;
    const int p = atomicAdd(&cnt[d], 1);
    if (p < CAP) col[d * CAP + p] = s;
}

// ---------------------------------------------------------------- W1 transpose prep
// W1T[n][k] = (f16)W1[k][n]  (128 x 256 f16 = 64KB). One-time ~2us; removes
// the per-block per-kstep 16-scalar-strided B-gather from round-12 gemm1.
__global__ __launch_bounds__(256) void w1_transpose(const float* __restrict__ W1,
                                                    _Float16* __restrict__ W1T) {
    const int n = blockIdx.x;          // 0..127
    const int k = threadIdx.x;         // 0..255
    W1T[n * 256 + k] = (_Float16)W1[(size_t)k * 128 + n];
}

// ---------------------------------------------------------------- GEMM1 (f16 MFMA)
// Round-15: B-stationary, ZERO barriers in K-loop. Round-12 version was
// latency-bound (MfmaUtil 3.4%, VALU 8.8%, HBM 13.7%): 2 syncthreads + LDS
// round-trip for A + 16 strided scalar W1 loads per thread per k-step vs
// only 8 MFMA/wave. Now: whole W1T preloaded once to padded LDS (stride 264
// f16 -> 2-way bank alias = free); A streams global->reg->f16 (nontemporal,
// X has no reuse); M_rep=4 (64 rows/wave) -> 32 MFMA per 8 ds_read_b128 +
// 8 global dwordx4 per k-step; next-k A prefetched in regs.
// Round-16: f32x4 (ext_vector) for nontemporal loads — HIP_vector_type
// float4 is rejected by __builtin_nontemporal_load.
__global__ __launch_bounds__(256) void gemm1_mfma(const float* __restrict__ X,
                                                  const _Float16* __restrict__ W1T,
                                                  _Float16* __restrict__ H) {
    __shared__ _Float16 Bs[128][BSTR];   // 67.6 KB -> 2 blocks/CU

    const int tid  = threadIdx.x;
    const int wave = tid >> 6;
    const int lane = tid & 63;
    const int m16  = lane & 15;
    const int quad = lane >> 4;
    const int rowBase = blockIdx.x * 256 + wave * 64;

    // ---- preload whole W1T into LDS (16 x b128 per thread), once
#pragma unroll
    for (int i = 0; i < 16; ++i) {
        const int c  = tid + 256 * i;         // 4096 chunks of 16B
        const int n  = c >> 5;                // row (col of W1)
        const int kb = (c & 31) * 16;         // byte within row
        *(f16x8*)((char*)&Bs[n][0] + kb) = *(const f16x8*)((const char*)W1T + (size_t)c * 16);
    }
    __syncthreads();   // the only barrier in the kernel

    f32x4 acc[4][8] = {};
    f32x4 avA[8];

    auto loadA = [&](int k0) {
#pragma unroll
        for (int m = 0; m < 4; ++m) {
            int gr = rowBase + m * 16 + m16;
            gr = gr < N ? gr : N - 1;         // clamp (stores guarded)
            const f32x4* p = (const f32x4*)&X[(size_t)gr * 256 + k0 + quad * 8];
            avA[2 * m]     = __builtin_nontemporal_load(p);
            avA[2 * m + 1] = __builtin_nontemporal_load(p + 1);
        }
    };

    loadA(0);
    for (int k0 = 0; k0 < 256; k0 += 32) {
        f16x8 af[4];
#pragma unroll
        for (int m = 0; m < 4; ++m) {
            f16x8 h;
            h[0] = (_Float16)avA[2*m][0];   h[1] = (_Float16)avA[2*m][1];
            h[2] = (_Float16)avA[2*m][2];   h[3] = (_Float16)avA[2*m][3];
            h[4] = (_Float16)avA[2*m+1][0]; h[5] = (_Float16)avA[2*m+1][1];
            h[6] = (_Float16)avA[2*m+1][2]; h[7] = (_Float16)avA[2*m+1][3];
            af[m] = h;
        }
        if (k0 + 32 < 256) loadA(k0 + 32);    // prefetch next tile into regs
#pragma unroll
        for (int nt = 0; nt < 8; ++nt) {
            const f16x8 bf = *(const f16x8*)&Bs[nt * 16 + m16][k0 + quad * 8];
#pragma unroll
            for (int m = 0; m < 4; ++m)
                acc[m][nt] = __builtin_amdgcn_mfma_f32_16x16x32_f16(af[m], bf, acc[m][nt], 0, 0, 0);
        }
    }

    // ---- epilogue: C/D layout col=lane&15, row=quad*4+r (verified convention)
#pragma unroll
    for (int m = 0; m < 4; ++m)
#pragma unroll
        for (int nt = 0; nt < 8; ++nt)
#pragma unroll
            for (int r = 0; r < 4; ++r) {
                const int gm = rowBase + m * 16 + quad * 4 + r;
                if (gm < N) H[(size_t)gm * 128 + nt * 16 + m16] = (_Float16)acc[m][nt][r];
            }
}

// ---------------------------------------------------------------- Fused agg1 + gemm2
// One wave per node; lane l owns feats [2l, 2l+1]; depth-4 double-buffered
// prefetch (proven best). Two half-range launches for profiler visibility.
__global__ __launch_bounds__(256) void agg1_gemm2(const _Float16* __restrict__ H,
                                                  const int* __restrict__ cnt,
                                                  const int* __restrict__ col,
                                                  const float* __restrict__ b1,
                                                  const float* __restrict__ W2,
                                                  float* __restrict__ Z,
                                                  int nbase, int ncount) {
    const int nr   = (blockIdx.x * blockDim.x + threadIdx.x) >> 6;
    const int lane = threadIdx.x & 63;
    if (nr >= ncount) return;
    const int n = nbase + nr;
    const int c = min(cnt[n], CAP);

    int sv = n;
    if (lane < c) sv = col[n * CAP + lane];
    const float dvw = rsqrtf((float)cnt[sv] + 1.0f);
    const float dv  = (lane <= c) ? dvw : 0.0f;

    const _Float16* hbase = H + lane * 2;
    const int ned4 = (c + 1 + 3) & ~3;

    f16x2 va[4]; float wa[4];
#pragma unroll
    for (int t = 0; t < 4; ++t) {
        const int   e = min(t, 63);
        const int   s = __shfl(sv, e);
        wa[t]         = __shfl(dv, e);
        va[t] = *(const f16x2*)&hbase[(size_t)s * 128];
    }
    float ax = 0.f, ay = 0.f;
    for (int j = 4; j < ned4; j += 4) {
        f16x2 vb[4]; float wb[4];
#pragma unroll
        for (int t = 0; t < 4; ++t) {
            const int   e = min(j + t, 63);
            const int   s = __shfl(sv, e);
            wb[t]         = __shfl(dv, e);
            vb[t] = *(const f16x2*)&hbase[(size_t)s * 128];
        }
#pragma unroll
        for (int t = 0; t < 4; ++t) {
            ax = fmaf(wa[t], (float)va[t][0], ax);
            ay = fmaf(wa[t], (float)va[t][1], ay);
            va[t] = vb[t]; wa[t] = wb[t];
        }
    }
#pragma unroll
    for (int t = 0; t < 4; ++t) {
        ax = fmaf(wa[t], (float)va[t][0], ax);
        ay = fmaf(wa[t], (float)va[t][1], ay);
    }

    const float dn = __shfl(dv, c);         // dinv[n]
    const float2 b = *(const float2*)&b1[lane * 2];
    const float hr0 = fmaxf(ax * dn + b.x, 0.f);
    const float hr1 = fmaxf(ay * dn + b.y, 0.f);

    const float4 wa0 = *(const float4*)&W2[(size_t)(lane * 2) * 8];
    const float4 wa1 = *(const float4*)&W2[(size_t)(lane * 2) * 8 + 4];
    const float4 wb0 = *(const float4*)&W2[(size_t)(lane * 2 + 1) * 8];
    const float4 wb1 = *(const float4*)&W2[(size_t)(lane * 2 + 1) * 8 + 4];
    float p[8];
    p[0] = hr0 * wa0.x + hr1 * wb0.x;
    p[1] = hr0 * wa0.y + hr1 * wb0.y;
    p[2] = hr0 * wa0.z + hr1 * wb0.z;
    p[3] = hr0 * wa0.w + hr1 * wb0.w;
    p[4] = hr0 * wa1.x + hr1 * wb1.x;
    p[5] = hr0 * wa1.y + hr1 * wb1.y;
    p[6] = hr0 * wa1.z + hr1 * wb1.z;
    p[7] = hr0 * wa1.w + hr1 * wb1.w;
#pragma unroll
    for (int off = 32; off > 0; off >>= 1)
#pragma unroll
        for (int j = 0; j < 8; ++j) p[j] += __shfl_xor(p[j], off);
    if (lane == 0) {
        *(float4*)&Z[(size_t)n * 8]     = make_float4(p[0], p[1], p[2], p[3]);
        *(float4*)&Z[(size_t)n * 8 + 4] = make_float4(p[4], p[5], p[6], p[7]);
    }
}

// ---------------------------------------------------------------- Aggregation layer 2 (F=8)
__global__ __launch_bounds__(64) void agg2(const float* __restrict__ Z,
                                           const int* __restrict__ cnt,
                                           const int* __restrict__ col,
                                           const float* __restrict__ b2,
                                           float* __restrict__ ZA) {
    const int n = blockIdx.x * blockDim.x + threadIdx.x;
    if (n >= N) return;
    const int c = min(cnt[n], CAP);
    float acc[8] = {};

    float4 va0[4], va1[4]; float wv[4];
#pragma unroll
    for (int t = 0; t < 4; ++t) {
        const int s = (t < c) ? col[n * CAP + t] : n;
        wv[t]  = (t < c) ? rsqrtf((float)cnt[s] + 1.0f) : 0.0f;
        va0[t] = *(const float4*)&Z[(size_t)s * 8];
        va1[t] = *(const float4*)&Z[(size_t)s * 8 + 4];
    }
    for (int j = 4; j + 4 <= c + 4; j += 4) {
        float4 vb0[4], vb1[4]; float wb[4];
#pragma unroll
        for (int t = 0; t < 4; ++t) {
            const int jt = j + t;
            const int s  = (jt < c) ? col[n * CAP + jt] : n;
            wb[t]  = (jt < c) ? rsqrtf((float)cnt[s] + 1.0f) : 0.0f;
            vb0[t] = *(const float4*)&Z[(size_t)s * 8];
            vb1[t] = *(const float4*)&Z[(size_t)s * 8 + 4];
        }
#pragma unroll
        for (int t = 0; t < 4; ++t) {
            const float w = wv[t];
            acc[0] = fmaf(w, va0[t].x, acc[0]); acc[1] = fmaf(w, va0[t].y, acc[1]);
            acc[2] = fmaf(w, va0[t].z, acc[2]); acc[3] = fmaf(w, va0[t].w, acc[3]);
            acc[4] = fmaf(w, va1[t].x, acc[4]); acc[5] = fmaf(w, va1[t].y, acc[5]);
            acc[6] = fmaf(w, va1[t].z, acc[6]); acc[7] = fmaf(w, va1[t].w, acc[7]);
            va0[t] = vb0[t]; va1[t] = vb1[t]; wv[t] = wb[t];
        }
    }
#pragma unroll
    for (int t = 0; t < 4; ++t) {
        const float w = wv[t];
        acc[0] = fmaf(w, va0[t].x, acc[0]); acc[1] = fmaf(w, va0[t].y, acc[1]);
        acc[2] = fmaf(w, va0[t].z, acc[2]); acc[3] = fmaf(w, va0[t].w, acc[3]);
        acc[4] = fmaf(w, va1[t].x, acc[4]); acc[5] = fmaf(w, va1[t].y, acc[5]);
        acc[6] = fmaf(w, va1[t].z, acc[6]); acc[7] = fmaf(w, va1[t].w, acc[7]);
    }

    const float dn = rsqrtf((float)c + 1.0f);
    const float4 zn0 = *(const float4*)&Z[(size_t)n * 8];
    const float4 zn1 = *(const float4*)&Z[(size_t)n * 8 + 4];
    float o[8];
    o[0] = (acc[0] + dn * zn0.x) * dn + b2[0];
    o[1] = (acc[1] + dn * zn0.y) * dn + b2[1];
    o[2] = (acc[2] + dn * zn0.z) * dn + b2[2];
    o[3] = (acc[3] + dn * zn0.w) * dn + b2[3];
    o[4] = (acc[4] + dn * zn1.x) * dn + b2[4];
    o[5] = (acc[5] + dn * zn1.y) * dn + b2[5];
    o[6] = (acc[6] + dn * zn1.z) * dn + b2[6];
    o[7] = (acc[7] + dn * zn1.w) * dn + b2[7];
    *(float4*)&ZA[(size_t)n * 8]     = make_float4(o[0], o[1], o[2], o[3]);
    *(float4*)&ZA[(size_t)n * 8 + 4] = make_float4(o[4], o[5], o[6], o[7]);
}

// ---------------------------------------------------------------- Edge scoring
__global__ __launch_bounds__(256) void score(const float* __restrict__ ZA,
                                             const int* __restrict__ pe,
                                             const int* __restrict__ ne,
                                             float* __restrict__ out) {
    const int e = blockIdx.x * blockDim.x + threadIdx.x;
    if (e >= ES) return;
    int a, b;
    if (e < EP) { a = pe[e];      b = pe[EP + e]; }
    else        { a = ne[e - EP]; b = ne[e];      }
    const float4 xa0 = *(const float4*)&ZA[(size_t)a * 8];
    const float4 xa1 = *(const float4*)&ZA[(size_t)a * 8 + 4];
    const float4 xb0 = *(const float4*)&ZA[(size_t)b * 8];
    const float4 xb1 = *(const float4*)&ZA[(size_t)b * 8 + 4];
    out[e] = xa0.x * xb0.x + xa0.y * xb0.y + xa0.z * xb0.z + xa0.w * xb0.w +
             xa1.x * xb1.x + xa1.y * xb1.y + xa1.z * xb1.z + xa1.w * xb1.w;
}

// ---------------------------------------------------------------- launch

extern "C" void kernel_launch(void* const* d_in, const int* in_sizes, int n_in,
                              void* d_out, int out_size, void* d_ws, size_t ws_size,
                              hipStream_t stream) {
    const float* x  = (const float*)d_in[0];
    const int*   ei = (const int*)d_in[1];   // [2, 1.6M] row-major
    const int*   pe = (const int*)d_in[2];   // [2, 200k]
    const int*   ne = (const int*)d_in[3];   // [2, 200k]
    const float* W1 = (const float*)d_in[4];
    const float* b1 = (const float*)d_in[5];
    const float* W2 = (const float*)d_in[6];
    const float* b2 = (const float*)d_in[7];
    float* out = (float*)d_out;

    char* ws = (char*)d_ws;
    size_t off = 0;
    auto carve = [&](size_t bytes) {
        char* p = ws + off;
        off += (bytes + 255) & ~(size_t)255;
        return p;
    };
    int*       cnt  = (int*)      carve((size_t)N * sizeof(int));            // 0.4 MB
    int*       gcnt = (int*)      carve((size_t)XG * sizeof(int));           // 32 B (adjacent to cnt)
    unsigned*  eb   = (unsigned*) carve((size_t)XG * SEGCAP * sizeof(unsigned)); // 7.0 MB
    int*       col  = (int*)      carve((size_t)N * CAP * sizeof(int));      // 25.6 MB
    _Float16*  H    = (_Float16*) carve((size_t)N * 128 * sizeof(_Float16)); // 25.6 MB
    float*     Z    = (float*)    carve((size_t)N * 8 * sizeof(float));      // 3.2 MB
    float*     ZA   = (float*)    carve((size_t)N * 8 * sizeof(float));      // 3.2 MB
    _Float16*  W1T  = (_Float16*) carve((size_t)128 * 256 * sizeof(_Float16)); // 64 KB

    // one memset covers cnt + gcnt (gcnt carved immediately after cnt)
    hipMemsetAsync(cnt, 0, (size_t)((char*)gcnt - (char*)cnt) + XG * sizeof(int), stream);
    partition_edges<<<NPB, PBS, 0, stream>>>(ei, gcnt, eb);
    w1_transpose   <<<128, 256, 0, stream>>>(W1, W1T);
    fill_buckets2  <<<XG * (SEGCAP / 256), 256, 0, stream>>>(eb, gcnt, cnt, col);
    gemm1_mfma     <<<(N + 255) / 256, 256, 0, stream>>>(x, W1T, H);
    agg1_gemm2     <<<(NH * 64 + 255) / 256, 256, 0, stream>>>(H, cnt, col, b1, W2, Z, 0, NH);
    agg1_gemm2     <<<((N - NH) * 64 + 255) / 256, 256, 0, stream>>>(H, cnt, col, b1, W2, Z, NH, N - NH);
    agg2           <<<(N + 63) / 64, 64, 0, stream>>>(Z, cnt, col, b2, ZA);
    score          <<<(ES + 255) / 256, 256, 0, stream>>>(ZA, pe, ne, out);
}